// Round 4
// baseline (276.556 us; speedup 1.0000x reference)
//
#include <hip/hip_runtime.h>

#define INSZ   2048
#define NH1    256
#define NH2    64
#define NB     8
#define BATCH  16384

#define TS        32                 // rows per block-tile (v10: halved -> 2 blocks/CU)
#define MAXTILES  (BATCH / TS)       // 512 (worst case: all samples in one bucket)
#define GRIDX     (NB * MAXTILES)    // 4096

// W1f: [bkt][kb(64)][cb(16)][lane(64)][8] bf16   (unchanged)
#define W1F_U4   (NB * 64 * 16 * 64)        // 524288 uint4
#define W2F_U4   (NB * 8 * 4 * 64)          // 16384 uint4

// ws layout (bytes)
#define META_OFF  0                  // 32 ints: cnt[8], off[8], cursor[8]
#define ORDER_OFF 1024               // 16384 ints
#define W1F_OFF   (1024 + BATCH * 4)            // 66560
#define W2F_OFF   (W1F_OFF + W1F_U4 * 16)       // 8,455,168
#define WS_NEED   (W2F_OFF + W2F_U4 * 16)       // 8,717,312

typedef float f2  __attribute__((ext_vector_type(2)));
typedef float f4  __attribute__((ext_vector_type(4)));
typedef float f32x4 __attribute__((ext_vector_type(4)));
typedef short bf16x8 __attribute__((ext_vector_type(8)));

__device__ __forceinline__ unsigned short f2bf(float f) {
    unsigned u = __float_as_uint(f);
    u += 0x7fffu + ((u >> 16) & 1u);   // RNE
    return (unsigned short)(u >> 16);
}
__device__ __forceinline__ float clamp01(float v) { return fminf(fmaxf(v, 0.0f), 1.0f); }
__device__ __forceinline__ unsigned pack2(float a, float b) {
    return (unsigned)f2bf(a) | ((unsigned)f2bf(b) << 16);
}

// ============================ pre-pass kernels ============================

__global__ void k_countscan(const int* __restrict__ idx, int* __restrict__ meta) {
    __shared__ int scnt[NB];
    int t = threadIdx.x;
    if (t < NB) scnt[t] = 0;
    __syncthreads();
    int local[NB];
#pragma unroll
    for (int bb = 0; bb < NB; bb++) local[bb] = 0;
    for (int i = t; i < BATCH; i += 1024) {
        int b = idx[i];
#pragma unroll
        for (int bb = 0; bb < NB; bb++) local[bb] += (b == bb) ? 1 : 0;
    }
#pragma unroll
    for (int bb = 0; bb < NB; bb++) {
        int v = local[bb];
        v += __shfl_xor(v, 1);  v += __shfl_xor(v, 2);  v += __shfl_xor(v, 4);
        v += __shfl_xor(v, 8);  v += __shfl_xor(v, 16); v += __shfl_xor(v, 32);
        if ((t & 63) == 0) atomicAdd(&scnt[bb], v);
    }
    __syncthreads();
    if (t == 0) {
        int run = 0;
        for (int b = 0; b < NB; b++) {
            int c = scnt[b];
            meta[b]      = c;
            meta[8 + b]  = run;
            meta[16 + b] = run;   // scatter cursor
            run += c;
        }
    }
}

__global__ void k_scatter(const int* __restrict__ idx, int* __restrict__ meta,
                          int* __restrict__ order) {
    __shared__ int wcnt[16][NB];
    __shared__ int sbase[NB];
    int t = threadIdx.x;
    int i = blockIdx.x * 1024 + t;
    int b = idx[i];
    int wv = t >> 6, lane = t & 63;
    unsigned long long mymask = 0;
#pragma unroll
    for (int bb = 0; bb < NB; bb++) {
        unsigned long long m = __ballot(b == bb);
        if (b == bb) mymask = m;
        if (lane == bb) wcnt[wv][bb] = (int)__popcll(m);
    }
    int myrank = (int)__popcll(mymask & ((1ull << lane) - 1ull));
    __syncthreads();
    if (t < NB) {
        int sum = 0;
        for (int w2 = 0; w2 < 16; w2++) { int c = wcnt[w2][t]; wcnt[w2][t] = sum; sum += c; }
        sbase[t] = atomicAdd(&meta[16 + t], sum);
    }
    __syncthreads();
    order[sbase[b] + wcnt[wv][b] + myrank] = i;
}

// pack W1/W2 into per-lane MFMA B-fragment order (bf16)
__global__ void k_pack(const float* __restrict__ W1, const float* __restrict__ W2,
                       uint4* __restrict__ W1f, uint4* __restrict__ W2f) {
    int u = blockIdx.x * 256 + threadIdx.x;
    if (u < W1F_U4) {
        int lane = u & 63, cb = (u >> 6) & 15, kb = (u >> 10) & 63, bkt = u >> 16;
        int l15 = lane & 15, quad = lane >> 4;
        const float* p = W1 + (size_t)(bkt * NH1 + cb * 16 + l15) * INSZ + kb * 32 + quad * 8;
        f4 lo = *(const f4*)p, hi = *(const f4*)(p + 4);
        uint4 o;
        o.x = pack2(lo[0], lo[1]); o.y = pack2(lo[2], lo[3]);
        o.z = pack2(hi[0], hi[1]); o.w = pack2(hi[2], hi[3]);
        W1f[u] = o;
    } else {
        int v = u - W1F_U4;
        if (v >= W2F_U4) return;
        int lane = v & 63, cg2 = (v >> 6) & 3, kb2 = (v >> 8) & 7, bkt = v >> 11;
        int l15 = lane & 15, quad = lane >> 4;
        const float* p = W2 + (size_t)(bkt * NH2 + cg2 * 16 + l15) * NH1 + kb2 * 32 + quad * 8;
        f4 lo = *(const f4*)p, hi = *(const f4*)(p + 4);
        uint4 o;
        o.x = pack2(lo[0], lo[1]); o.y = pack2(lo[2], lo[3]);
        o.z = pack2(hi[0], hi[1]); o.w = pack2(hi[2], hi[3]);
        W2f[v] = o;
    }
}

// ============================ main fused kernel ============================
// v10 = v8 step structure at TS=32: 512 active blocks -> 2 independent
// blocks per CU. Source-level pipelining (v7/v8/v9) plateaued at ~80 us
// because every CU held exactly ONE barrier-locked block: any per-step
// stall was dead time. Two co-resident blocks interleave their stalls
// (m114 mechanism); same-CU pairs (b, b+256) share the bucket -> shared W
// stream in L1/L2. Per-wave work: 2 A-frags x 2 B-frags = 4 MFMA/step.
// All 512 threads stage x as float2 (row t>>4, floats (t&15)*2).

__global__ __launch_bounds__(512, 4) void fused_v10(
    const float* __restrict__ x, const int* __restrict__ meta,
    const int* __restrict__ order,
    const short* __restrict__ W1f, const short* __restrict__ W2f,
    const float* __restrict__ b1, const float* __restrict__ b2,
    const float* __restrict__ W3, const float* __restrict__ b3,
    float* __restrict__ out)
{
    const int bkt  = blockIdx.x & 7;
    const int tile = blockIdx.x >> 3;     // identity: actives = first ~512 blocks
    const int cnt  = meta[bkt];
    const int base = tile * TS;
    if (base >= cnt) return;
    const int off = meta[8 + bkt];

    __shared__ short sX[2][TS * 40];     // 2 x 2.5 KB  x k-step (bf16, stride 40)
    __shared__ short sh1[TS * 264];      // 16.9 KB     h1 (bf16)
    __shared__ float sPart[4][TS];       // 0.5 KB      layer-3 partials

    const int t = threadIdx.x;
    const int lane = t & 63, w = t >> 6;
    const int l15 = lane & 15, quad = lane >> 4;

    // x staging: thread t -> row t>>4, 2 floats at (t&15)*2
    const int xr = t >> 4, kq = t & 15;
    int ir = base + xr; if (ir > cnt - 1) ir = cnt - 1;
    const float* xtp = x + (size_t)order[off + ir] * INSZ + kq * 2;
    const int sxo = xr * 40 + kq * 2;

    // per-wave W1 fragment pointer: frag (kb, cb=2w+j) at kb*8192 + j*512 (+lane*8)
    const short* wp = W1f + ((size_t)bkt << 19) + (size_t)(2 * w) * 512 + lane * 8;

    f32x4 acc[2][2];
#pragma unroll
    for (int f = 0; f < 2; f++)
#pragma unroll
        for (int j = 0; j < 2; j++) acc[f][j] = (f32x4)0.0f;

    bf16x8 wA0, wA1, wB0, wB1;   // W reg double-buffer: set = kb&1, reloaded at use-step
    f2 xs0, xs1, xs2, xs3;       // x pipeline: slot s holds x(m), m%4==s, depth 4

    // ---- prologue: W(0),W(1) -> regs; x(0) -> LDS buf0; x(1..3) -> slots ----
    wA0 = *(const bf16x8*)(wp);
    wA1 = *(const bf16x8*)(wp + 512);
    wB0 = *(const bf16x8*)(wp + 8192);
    wB1 = *(const bf16x8*)(wp + 8192 + 512);
    {
        f2 x0 = *(const f2*)xtp;
        xs1 = *(const f2*)(xtp + 32);
        xs2 = *(const f2*)(xtp + 64);
        xs3 = *(const f2*)(xtp + 96);
        *(unsigned*)&sX[0][sxo] = pack2(x0[0], x0[1]);
    }

    // Per step KB: [load x(KB+4) -> slot KB%4] | lgkm(0)+barrier |
    //   ds_read 2 A-frags | 4 MFMA on W(KB) | pack+ds_write x(KB+1) from
    //   slot (KB+1)%4 | [reload freed W set with W(KB+2)].
#define L1_STEP(KB, XL, XW, WU0, WU1)                                                   \
    {                                                                                   \
        if ((KB) < 60) XL = *(const f2*)(xtp + ((KB) + 4) * 32);                        \
        asm volatile("s_waitcnt lgkmcnt(0)" ::: "memory");                              \
        __builtin_amdgcn_s_barrier();                                                   \
        asm volatile("" ::: "memory");                                                  \
        const int P = (KB) & 1;                                                         \
        bf16x8 a0 = *(const bf16x8*)&sX[P][(l15)      * 40 + quad * 8];                 \
        bf16x8 a1 = *(const bf16x8*)&sX[P][(16 + l15) * 40 + quad * 8];                 \
        acc[0][0] = __builtin_amdgcn_mfma_f32_16x16x32_bf16(a0, WU0, acc[0][0], 0,0,0); \
        acc[0][1] = __builtin_amdgcn_mfma_f32_16x16x32_bf16(a0, WU1, acc[0][1], 0,0,0); \
        acc[1][0] = __builtin_amdgcn_mfma_f32_16x16x32_bf16(a1, WU0, acc[1][0], 0,0,0); \
        acc[1][1] = __builtin_amdgcn_mfma_f32_16x16x32_bf16(a1, WU1, acc[1][1], 0,0,0); \
        if ((KB) < 63) {                                                                \
            *(unsigned*)&sX[P ^ 1][sxo] = pack2(XW[0], XW[1]);                          \
        }                                                                               \
        if ((KB) < 62) {                                                                \
            WU0 = *(const bf16x8*)(wp + (size_t)((KB) + 2) * 8192);                     \
            WU1 = *(const bf16x8*)(wp + (size_t)((KB) + 2) * 8192 + 512);               \
        }                                                                               \
    }

#pragma unroll 1
    for (int kb = 0; kb < 64; kb += 4) {
        L1_STEP(kb + 0, xs0, xs1, wA0, wA1)
        L1_STEP(kb + 1, xs1, xs2, wB0, wB1)
        L1_STEP(kb + 2, xs2, xs3, wA0, wA1)
        L1_STEP(kb + 3, xs3, xs0, wB0, wB1)
    }
#undef L1_STEP

    // ---- layer-1 epilogue: bias + clip01 -> sh1 (32 rows x 256 cols) ----
#pragma unroll
    for (int j = 0; j < 2; j++) {
        int col = w * 32 + j * 16 + l15;
        float bias = b1[bkt * NH1 + col];
#pragma unroll
        for (int f = 0; f < 2; f++)
#pragma unroll
            for (int r = 0; r < 4; r++) {
                int row = f * 16 + quad * 4 + r;
                sh1[row * 264 + col] = (short)f2bf(clamp01(acc[f][j][r] + bias));
            }
    }
    __syncthreads();

    // ---- layer 2: wave w -> h2 rows (w&1)*16..+15, cols (w>>1)*16..+15 ----
    const int rw = w & 1, cg2 = w >> 1;
    f32x4 c2 = (f32x4)0.0f;
    const short* w2p = W2f + (size_t)bkt * 16384 + lane * 8;
#pragma unroll
    for (int kb2 = 0; kb2 < 8; kb2++) {
        bf16x8 a2 = *(const bf16x8*)&sh1[(rw * 16 + l15) * 264 + kb2 * 32 + quad * 8];
        bf16x8 bw = *(const bf16x8*)(w2p + (kb2 * 4 + cg2) * 512);
        c2 = __builtin_amdgcn_mfma_f32_16x16x32_bf16(a2, bw, c2, 0, 0, 0);
    }

    // ---- layer-2 epilogue + layer-3 partial dot ----
    {
        int n2 = cg2 * 16 + l15;
        float bias2 = b2[bkt * NH2 + n2];
        float w3v   = W3[bkt * NH2 + n2];
        float s[4];
#pragma unroll
        for (int r = 0; r < 4; r++)
            s[r] = clamp01(c2[r] + bias2) * w3v;
#pragma unroll
        for (int r = 0; r < 4; r++) {
            float pp = s[r];
            pp += __shfl_xor(pp, 1); pp += __shfl_xor(pp, 2);
            pp += __shfl_xor(pp, 4); pp += __shfl_xor(pp, 8);
            if (l15 == 0) sPart[cg2][rw * 16 + quad * 4 + r] = pp;
        }
    }
    __syncthreads();
    if (t < TS && base + t < cnt)
        out[order[off + base + t]] =
            sPart[0][t] + sPart[1][t] + sPart[2][t] + sPart[3][t] + b3[bkt];
}

// ============================ naive fallback ============================

__global__ void naive_mlp(const float* __restrict__ x, const int* __restrict__ idx,
                          const float* __restrict__ W1, const float* __restrict__ b1,
                          const float* __restrict__ W2, const float* __restrict__ b2,
                          const float* __restrict__ W3, const float* __restrict__ b3,
                          float* __restrict__ out)
{
    int i = blockIdx.x;
    int b = idx[i];
    __shared__ float sx[INSZ];
    __shared__ float sh1n[NH1];
    __shared__ float sh2n[NH2];
    for (int t = threadIdx.x; t < INSZ; t += 256) sx[t] = x[(size_t)i * INSZ + t];
    __syncthreads();
    int j = threadIdx.x;
    {
        const float* wr = W1 + (size_t)(b * NH1 + j) * INSZ;
        float acc = b1[b * NH1 + j];
        for (int k = 0; k < INSZ; k++) acc += sx[k] * wr[k];
        sh1n[j] = fminf(fmaxf(acc, 0.f), 1.f);
    }
    __syncthreads();
    if (j < NH2) {
        const float* wr = W2 + (size_t)(b * NH2 + j) * NH1;
        float acc = b2[b * NH2 + j];
        for (int k = 0; k < NH1; k++) acc += sh1n[k] * wr[k];
        sh2n[j] = fminf(fmaxf(acc, 0.f), 1.f);
    }
    __syncthreads();
    if (j == 0) {
        float acc = b3[b];
        for (int k = 0; k < NH2; k++) acc += sh2n[k] * W3[b * NH2 + k];
        out[i] = acc;
    }
}

extern "C" void kernel_launch(void* const* d_in, const int* in_sizes, int n_in,
                              void* d_out, int out_size, void* d_ws, size_t ws_size,
                              hipStream_t stream) {
    const float* x  = (const float*)d_in[0];
    const int* bidx = (const int*)d_in[1];
    const float* W1 = (const float*)d_in[2];
    const float* b1 = (const float*)d_in[3];
    const float* W2 = (const float*)d_in[4];
    const float* b2 = (const float*)d_in[5];
    const float* W3 = (const float*)d_in[6];
    const float* b3 = (const float*)d_in[7];
    float* out = (float*)d_out;

    if (ws_size >= (size_t)WS_NEED) {
        char* ws = (char*)d_ws;
        int*   meta  = (int*)(ws + META_OFF);
        int*   order = (int*)(ws + ORDER_OFF);
        uint4* W1f   = (uint4*)(ws + W1F_OFF);
        uint4* W2f   = (uint4*)(ws + W2F_OFF);

        k_countscan<<<1, 1024, 0, stream>>>(bidx, meta);
        k_scatter<<<BATCH / 1024, 1024, 0, stream>>>(bidx, meta, order);
        k_pack<<<(W1F_U4 + W2F_U4) / 256, 256, 0, stream>>>(W1, W2, W1f, W2f);
        fused_v10<<<GRIDX, 512, 0, stream>>>(x, meta, order,
                                             (const short*)W1f, (const short*)W2f,
                                             b1, b2, W3, b3, out);
    } else {
        naive_mlp<<<BATCH, 256, 0, stream>>>(x, bidx, W1, b1, W2, b2, W3, b3, out);
    }
}